// Round 19
// baseline (28.708 us; speedup 1.0000x reference)
//
#include <hip/hip_runtime.h>
#include <stdint.h>

#define D_DIM 256
#define K_CTR 1024
#define B_ROWS 16384
#define BM 32
#define NSTRIP (B_ROWS / BM)   // 512

typedef float f32x4 __attribute__((ext_vector_type(4)));
typedef float f32x2 __attribute__((ext_vector_type(2)));
typedef long long i64x2 __attribute__((ext_vector_type(2)));
typedef unsigned int u32x4 __attribute__((ext_vector_type(4)));

// Pack 4 f32 -> 4 fp8 e4m3 bytes (OCP, HW cvt).
static __device__ __forceinline__ unsigned cvt4_fp8(const float4 v) {
    int r = __builtin_amdgcn_cvt_pk_fp8_f32(v.x, v.y, 0, false);   // bytes 0-1
    r = __builtin_amdgcn_cvt_pk_fp8_f32(v.z, v.w, r, true);        // bytes 2-3
    return (unsigned)r;
}

// lgkm-only barrier: LDS handoffs need lgkmcnt(0)+s_barrier; global stores/loads
// stay in flight across it and drain under subsequent compute.
static __device__ __forceinline__ void barrier_lgkm() {
    asm volatile("s_waitcnt lgkmcnt(0)" ::: "memory");
    __builtin_amdgcn_s_barrier();
}

// Lane-l position within a row's 256B fragment image (d = 4l..4l+3).
static __device__ __forceinline__ unsigned lane_pos(int l) {
    return (unsigned)((l >> 4) * 64 + ((l >> 1) & 3) * 16 + ((l >> 3) & 1) * 8 + (l & 1) * 4);
}

// Prep v2 (R18): blocks 0..2047: x -> fp8 pre-swizzled As-image (xb) + xsq;
// blocks 2048..2303: centers -> fp8 fragment-major cbf + csq.
__global__ __launch_bounds__(256) void rbf_prep(const float* __restrict__ x,
                                                const float* __restrict__ centers,
                                                unsigned char* __restrict__ cbf,
                                                float* __restrict__ csq,
                                                unsigned char* __restrict__ xb,
                                                float* __restrict__ xsq) {
    const int w = threadIdx.x >> 6;
    const int l = threadIdx.x & 63;
    if (blockIdx.x < 2048) {
        #pragma unroll
        for (int i = 0; i < 2; ++i) {
            const int row = blockIdx.x * 8 + i * 4 + w;
            const float4 v = *reinterpret_cast<const float4*>(x + (size_t)row * D_DIM + l * 4);
            float s = v.x * v.x + v.y * v.y + v.z * v.z + v.w * v.w;
            const unsigned u = cvt4_fp8(v);
            const int strip = row >> 5, rloc = row & 31;
            *reinterpret_cast<unsigned*>(xb + (size_t)strip * 8192 + rloc * 256
                + (lane_pos(l) ^ ((unsigned)(rloc & 7) << 4))) = u;
            #pragma unroll
            for (int off = 1; off < 64; off <<= 1) s += __shfl_xor(s, off);
            if (l == 0) xsq[row] = s;
        }
    } else {
        const int c0 = (blockIdx.x - 2048) * 4 + w;
        const float4 v = *reinterpret_cast<const float4*>(centers + c0 * D_DIM + l * 4);
        float s = v.x * v.x + v.y * v.y + v.z * v.z + v.w * v.w;
        const unsigned u = cvt4_fp8(v);
        const unsigned off = (unsigned)((c0 >> 4) * 4096 + (l >> 4) * 1024
                           + (((l >> 1) & 3) * 16 + (c0 & 15)) * 16
                           + ((l >> 3) & 1) * 8 + (l & 1) * 4);
        *reinterpret_cast<unsigned*>(cbf + off) = u;
        #pragma unroll
        for (int off2 = 1; off2 < 64; off2 <<= 1) s += __shfl_xor(s, off2);
        if (l == 0) csq[c0] = s;
    }
}

// Main: PRODUCER-CONSUMER wave specialization. 512 thr = 4 compute waves (w<4)
// + 4 store waves (w>=4). Per phase ph (8 x 128 cols): compute waves run 2
// colgroup-steps {B ping-pong prefetch, 16 MFMA (setprio), exp2 -> obuf[ph&1]};
// store waves write phase ph-1 from obuf[(ph-1)&1] (8 rows x 512B single-segment
// each). vmcnt is per-wave: store drain NEVER gates MFMA issue. Barrier counts
// identical across roles (1 prologue + 8 loop); tail store after the loop.
__global__ __launch_bounds__(512, 4) void rbf_main(const unsigned char* __restrict__ xb,
                                                   const float* __restrict__ xsq,
                                                   const unsigned char* __restrict__ cbf,
                                                   const float* __restrict__ csq,
                                                   const float* __restrict__ betas,
                                                   float* __restrict__ out) {
    __shared__ __align__(16) unsigned char As[BM * D_DIM];   // 8 KB fp8 image
    __shared__ __align__(16) float obuf[2][BM * 128];        // 2 x 16 KB, swizzled

    const int tid = threadIdx.x;
    const int w = tid >> 6;
    const int l = tid & 63;
    const bool is_store = (w >= 4);
    // XCD-chunked bijective swizzle (512 = 8*64)
    const int strip = (blockIdx.x & 7) * 64 + (blockIdx.x >> 3);
    const int row0 = strip * BM;

    // ---- Prologue: copy precomputed As image (8 KB) into LDS (all waves) ----
    {
        const u32x4 v = *reinterpret_cast<const u32x4*>(xb + (size_t)strip * 8192 + tid * 16);
        *reinterpret_cast<u32x4*>(As + tid * 16) = v;
    }

    const int hk = l >> 4;
    const int lr = l & 15;
    const unsigned char* bwave = cbf + l * 16;

    // ---- Compute waves: issue B(step 0: colgroup w*2) before the barrier ----
    i64x2 bA[4], bB[4];
    if (!is_store) {
        const unsigned char* bbase = bwave + (w * 2) * 4096;
        #pragma unroll
        for (int p = 0; p < 4; ++p)
            bA[p] = *reinterpret_cast<const i64x2*>(bbase + p * 1024);
    }
    barrier_lgkm();   // As handoff

    // ---- Compute waves: hoist A frags + xsq ----
    i64x2 a[2][4];
    float xs0 = 0.f, xs1 = 0.f;
    if (!is_store) {
        #pragma unroll
        for (int m = 0; m < 2; ++m) {
            const int r = m * 16 + lr;
            #pragma unroll
            for (int p = 0; p < 4; ++p)
                a[m][p] = *reinterpret_cast<const i64x2*>(
                    As + r * 256 + ((unsigned)(p * 64 + hk * 16) ^ ((unsigned)(lr & 7) << 4)));
        }
        xs0 = xsq[row0 + lr];
        xs1 = xsq[row0 + 16 + lr];
    }
    const float LOG2E = 1.4426950408889634f;

    // Store-wave data registers (ping-pong; never reused while in flight).
    f32x2 svA[8] = {}, svB[8] = {};
    const int srow = (w - 4) * 8;    // store wave's first row

    #pragma unroll
    for (int ph = 0; ph < 8; ++ph) {
        if (!is_store) {
            // ---- 2 colgroup-steps: e=0 uses bA (prefetch bB), e=1 uses bB ----
            float* ob = obuf[ph & 1];
            #pragma unroll
            for (int e = 0; e < 2; ++e) {
                // Prefetch next step's B: e=0 -> (ph, w*2+1) into bB;
                //                         e=1 -> (ph+1, w*2) into bA.
                if (e == 0) {
                    const unsigned char* bbase = bwave + (ph * 8 + w * 2 + 1) * 4096;
                    #pragma unroll
                    for (int p = 0; p < 4; ++p)
                        bB[p] = *reinterpret_cast<const i64x2*>(bbase + p * 1024);
                } else if (ph < 7) {
                    const unsigned char* bbase = bwave + ((ph + 1) * 8 + w * 2) * 4096;
                    #pragma unroll
                    for (int p = 0; p < 4; ++p)
                        bA[p] = *reinterpret_cast<const i64x2*>(bbase + p * 1024);
                }
                const i64x2 (&bc)[4] = e ? bB : bA;

                // 16 MFMAs, 2 independent acc chains (T5: role diversity exists now)
                f32x4 acc[2] = {};
                __builtin_amdgcn_s_setprio(1);
                #pragma unroll
                for (int p = 0; p < 4; ++p)
                    #pragma unroll
                    for (int m = 0; m < 2; ++m) {
                        acc[m] = __builtin_amdgcn_mfma_f32_16x16x32_fp8_fp8(bc[p][0], a[m][p][0], acc[m], 0, 0, 0);
                        acc[m] = __builtin_amdgcn_mfma_f32_16x16x32_fp8_fp8(bc[p][1], a[m][p][1], acc[m], 0, 0, 0);
                    }
                __builtin_amdgcn_s_setprio(0);

                // Epilogue: exp2(fma(2*bt*log2e, acc, -bt*log2e*(xs+cs))) -> obuf
                const int cl = (w * 2 + e) * 16 + hk * 4;     // col within phase
                const f32x4 cs = *reinterpret_cast<const f32x4*>(csq + ph * 128 + cl);
                const f32x4 bt = *reinterpret_cast<const f32x4*>(betas + ph * 128 + cl);
                #pragma unroll
                for (int m = 0; m < 2; ++m) {
                    const int r = m * 16 + lr;
                    const float xsv = m ? xs1 : xs0;
                    f32x4 rv;
                    #pragma unroll
                    for (int j = 0; j < 4; ++j) {
                        const float btl2 = bt[j] * LOG2E;
                        const float cc = -btl2 * (xsv + cs[j]);
                        rv[j] = __builtin_exp2f(__builtin_fmaf(btl2 + btl2, acc[m][j], cc));
                    }
                    *reinterpret_cast<f32x4*>(reinterpret_cast<char*>(ob)
                        + r * 512 + ((unsigned)(cl * 4) ^ ((unsigned)(r & 7) << 4))) = rv;
                }
            }
        } else if (ph >= 1) {
            // ---- Store phase ph-1 from obuf[(ph-1)&1]: rows srow..srow+7 ----
            const char* ob = reinterpret_cast<const char*>(obuf[(ph - 1) & 1]);
            f32x2 (&sv)[8]  = (ph & 1) ? svA : svB;
            f32x2 (&svo)[8] = (ph & 1) ? svB : svA;
            asm volatile("" :: "v"(svo[0]), "v"(svo[3]), "v"(svo[5]), "v"(svo[7]));
            #pragma unroll
            for (int i = 0; i < 8; ++i) {
                const int r = srow + i;
                sv[i] = *reinterpret_cast<const f32x2*>(ob
                        + r * 512 + ((unsigned)(l * 8) ^ ((unsigned)(r & 7) << 4)));
            }
            #pragma unroll
            for (int i = 0; i < 8; ++i) {
                const int r = srow + i;
                *reinterpret_cast<f32x2*>(out + (size_t)(row0 + r) * K_CTR
                        + (ph - 1) * 128 + l * 2) = sv[i];
            }
        }
        barrier_lgkm();   // obuf handoff both directions (LDS-only)
    }

    // ---- Tail: store waves flush phase 7 (obuf[1]); no barrier needed ----
    if (is_store) {
        const char* ob = reinterpret_cast<const char*>(obuf[1]);
        #pragma unroll
        for (int i = 0; i < 8; ++i) {
            const int r = srow + i;
            const f32x2 v = *reinterpret_cast<const f32x2*>(ob
                    + r * 512 + ((unsigned)(l * 8) ^ ((unsigned)(r & 7) << 4)));
            *reinterpret_cast<f32x2*>(out + (size_t)(row0 + r) * K_CTR + 7 * 128 + l * 2) = v;
        }
    }
}

extern "C" void kernel_launch(void* const* d_in, const int* in_sizes, int n_in,
                              void* d_out, int out_size, void* d_ws, size_t ws_size,
                              hipStream_t stream) {
    const float* x       = (const float*)d_in[0];
    const float* centers = (const float*)d_in[1];
    const float* betas   = (const float*)d_in[2];
    float* out = (float*)d_out;

    unsigned char* cbf = (unsigned char*)d_ws;                        // 256 KB fp8 fragment-major centers
    float* csq = (float*)((char*)d_ws + 262144);                      // 4 KB c_sq
    unsigned char* xb  = (unsigned char*)d_ws + 262144 + 4096;        // 4 MB fp8 As-images
    float* xsq = (float*)((char*)d_ws + 262144 + 4096 + (size_t)NSTRIP * 8192);   // 64 KB x_sq

    rbf_prep<<<2048 + K_CTR / 4, 256, 0, stream>>>(x, centers, cbf, csq, xb, xsq);
    rbf_main<<<NSTRIP, 512, 0, stream>>>(xb, xsq, cbf, csq, betas, out);
}

// Round 20
// 26.601 us; speedup vs baseline: 1.0792x; 1.0792x over previous
//
#include <hip/hip_runtime.h>
#include <stdint.h>

#define D_DIM 256
#define K_CTR 1024
#define B_ROWS 16384
#define BM 32
#define NSTRIP (B_ROWS / BM)   // 512

typedef float f32x4 __attribute__((ext_vector_type(4)));
typedef float f32x2 __attribute__((ext_vector_type(2)));
typedef long long i64x2 __attribute__((ext_vector_type(2)));
typedef unsigned int u32x4 __attribute__((ext_vector_type(4)));

// Pack 4 f32 -> 4 fp8 e4m3 bytes (OCP, HW cvt).
static __device__ __forceinline__ unsigned cvt4_fp8(const float4 v) {
    int r = __builtin_amdgcn_cvt_pk_fp8_f32(v.x, v.y, 0, false);   // bytes 0-1
    r = __builtin_amdgcn_cvt_pk_fp8_f32(v.z, v.w, r, true);        // bytes 2-3
    return (unsigned)r;
}

// lgkm-only barrier: LDS handoffs need lgkmcnt(0)+s_barrier; global stores/loads
// stay in flight across it and drain under subsequent compute.
static __device__ __forceinline__ void barrier_lgkm() {
    asm volatile("s_waitcnt lgkmcnt(0)" ::: "memory");
    __builtin_amdgcn_s_barrier();
}

// Lane-l position within a row's 256B fragment image (d = 4l..4l+3):
// pos = p*64 + hk*16 + e*8 + j with p=l>>4, hk=(l>>1)&3, e=(l>>3)&1, j=(l&1)*4.
static __device__ __forceinline__ unsigned lane_pos(int l) {
    return (unsigned)((l >> 4) * 64 + ((l >> 1) & 3) * 16 + ((l >> 3) & 1) * 8 + (l & 1) * 4);
}

// Prep v2: (a) blocks 0..2047: x -> fp8 pre-swizzled As-image (xb, 4MB) + xsq;
//          (b) blocks 2048..2303: centers -> fp8 fragment-major cbf + csq.
// cbf layout: value c[col][d] at byte (col>>4)*4096 + p*1024 + (hk*16+(col&15))*16
// + e*8 + j  -> main's wave B-load (lane l) at p*1024 + l*16 is one 1KB dwordx4.
// xb layout: strip s, row r (0..31), byte = s*8192 + r*256 + (lane_pos ^ ((r&7)<<4))
// == exactly the LDS As image main builds; main just copies it in.
__global__ __launch_bounds__(256) void rbf_prep(const float* __restrict__ x,
                                                const float* __restrict__ centers,
                                                unsigned char* __restrict__ cbf,
                                                float* __restrict__ csq,
                                                unsigned char* __restrict__ xb,
                                                float* __restrict__ xsq) {
    const int w = threadIdx.x >> 6;
    const int l = threadIdx.x & 63;
    if (blockIdx.x < 2048) {
        // ---- x: 8 rows per block ----
        #pragma unroll
        for (int i = 0; i < 2; ++i) {
            const int row = blockIdx.x * 8 + i * 4 + w;
            const float4 v = *reinterpret_cast<const float4*>(x + (size_t)row * D_DIM + l * 4);
            float s = v.x * v.x + v.y * v.y + v.z * v.z + v.w * v.w;
            const unsigned u = cvt4_fp8(v);
            const int strip = row >> 5, rloc = row & 31;
            *reinterpret_cast<unsigned*>(xb + (size_t)strip * 8192 + rloc * 256
                + (lane_pos(l) ^ ((unsigned)(rloc & 7) << 4))) = u;
            #pragma unroll
            for (int off = 1; off < 64; off <<= 1) s += __shfl_xor(s, off);
            if (l == 0) xsq[row] = s;
        }
    } else {
        // ---- centers: 4 cols per block ----
        const int c0 = (blockIdx.x - 2048) * 4 + w;
        const float4 v = *reinterpret_cast<const float4*>(centers + c0 * D_DIM + l * 4);
        float s = v.x * v.x + v.y * v.y + v.z * v.z + v.w * v.w;
        const unsigned u = cvt4_fp8(v);
        const unsigned off = (unsigned)((c0 >> 4) * 4096 + (l >> 4) * 1024
                           + (((l >> 1) & 3) * 16 + (c0 & 15)) * 16
                           + ((l >> 3) & 1) * 8 + (l & 1) * 4);
        *reinterpret_cast<unsigned*>(cbf + off) = u;
        #pragma unroll
        for (int off2 = 1; off2 < 64; off2 <<= 1) s += __shfl_xor(s, off2);
        if (l == 0) csq[c0] = s;
    }
}

// Main: 512 thr (8 waves), block = 32 rows x 1024 cols, 8 phases of 128 cols.
// Prologue = straight 8KB copy of the precomputed As-image. Per phase:
// ping-pong B prefetch, 16 MFMA (2 acc chains), exp2 epilogue -> obuf[ph&1]
// (swizzled), lgkm-only barrier, single-segment 512B wave stores whose source
// registers ping-pong (asm keepalive) so in-flight store data is never
// overwritten -> store drain never serializes with the next phase's compute.
__global__ __launch_bounds__(512, 4) void rbf_main(const unsigned char* __restrict__ xb,
                                                   const float* __restrict__ xsq,
                                                   const unsigned char* __restrict__ cbf,
                                                   const float* __restrict__ csq,
                                                   const float* __restrict__ betas,
                                                   float* __restrict__ out) {
    __shared__ __align__(16) unsigned char As[BM * D_DIM];   // 8 KB fp8 image
    __shared__ __align__(16) float obuf[2][BM * 128];        // 2 x 16 KB, swizzled

    const int tid = threadIdx.x;
    const int w = tid >> 6;
    const int l = tid & 63;
    // XCD-chunked bijective swizzle (512 = 8*64)
    const int strip = (blockIdx.x & 7) * 64 + (blockIdx.x >> 3);
    const int row0 = strip * BM;

    // ---- Prologue: copy precomputed As image (8 KB) into LDS ----
    {
        const u32x4 v = *reinterpret_cast<const u32x4*>(xb + (size_t)strip * 8192 + tid * 16);
        *reinterpret_cast<u32x4*>(As + tid * 16) = v;
    }

    const int hk = l >> 4;
    const int lr = l & 15;
    const unsigned char* bwave = cbf + l * 16;

    // ---- Issue B(phase 0) BEFORE the barrier (stays in flight across it) ----
    i64x2 b0[4], b1[4];
    {
        const unsigned char* bbase = bwave + w * 4096;
        #pragma unroll
        for (int p = 0; p < 4; ++p)
            b0[p] = *reinterpret_cast<const i64x2*>(bbase + p * 1024);
    }
    barrier_lgkm();   // As handoff

    // ---- Hoist A frags once: 8 ds_read_b128 ----
    i64x2 a[2][4];
    #pragma unroll
    for (int m = 0; m < 2; ++m) {
        const int r = m * 16 + lr;
        #pragma unroll
        for (int p = 0; p < 4; ++p)
            a[m][p] = *reinterpret_cast<const i64x2*>(
                As + r * 256 + ((unsigned)(p * 64 + hk * 16) ^ ((unsigned)(lr & 7) << 4)));
    }
    const float xs0 = xsq[row0 + lr];
    const float xs1 = xsq[row0 + 16 + lr];
    const float LOG2E = 1.4426950408889634f;

    // Store-source register ping-pong (overwritten only one full phase later).
    f32x2 svA[4] = {}, svB[4] = {};

    #pragma unroll
    for (int ph = 0; ph < 8; ++ph) {
        const int colp = ph * 128;
        const i64x2 (&bc)[4] = (ph & 1) ? b1 : b0;
        i64x2 (&bn)[4] = (ph & 1) ? b0 : b1;

        // ---- Prefetch B(ph+1) ----
        if (ph < 7) {
            const unsigned char* bbase = bwave + ((ph + 1) * 8 + w) * 4096;
            #pragma unroll
            for (int p = 0; p < 4; ++p)
                bn[p] = *reinterpret_cast<const i64x2*>(bbase + p * 1024);
        }

        // ---- 16 MFMAs, 2 independent acc chains ----
        f32x4 acc[2] = {};
        #pragma unroll
        for (int p = 0; p < 4; ++p)
            #pragma unroll
            for (int m = 0; m < 2; ++m) {
                acc[m] = __builtin_amdgcn_mfma_f32_16x16x32_fp8_fp8(bc[p][0], a[m][p][0], acc[m], 0, 0, 0);
                acc[m] = __builtin_amdgcn_mfma_f32_16x16x32_fp8_fp8(bc[p][1], a[m][p][1], acc[m], 0, 0, 0);
            }

        // ---- Epilogue: exp2(fma(2*bt*log2e, acc, -bt*log2e*(xs+cs))) -> obuf ----
        float* ob = obuf[ph & 1];
        {
            const int cl = w * 16 + hk * 4;        // col within 128-col phase
            const f32x4 cs = *reinterpret_cast<const f32x4*>(csq + colp + cl);
            const f32x4 bt = *reinterpret_cast<const f32x4*>(betas + colp + cl);
            #pragma unroll
            for (int m = 0; m < 2; ++m) {
                const int r = m * 16 + lr;
                const float xsv = m ? xs1 : xs0;
                f32x4 rv;
                #pragma unroll
                for (int j = 0; j < 4; ++j) {
                    const float btl2 = bt[j] * LOG2E;
                    const float cc = -btl2 * (xsv + cs[j]);
                    rv[j] = __builtin_exp2f(__builtin_fmaf(btl2 + btl2, acc[m][j], cc));
                }
                *reinterpret_cast<f32x4*>(reinterpret_cast<char*>(ob)
                    + r * 512 + ((unsigned)(cl * 4) ^ ((unsigned)(r & 7) << 4))) = rv;
            }
        }
        barrier_lgkm();   // obuf handoff (LDS-only; global stores keep flowing)

        // ---- Stores: wave w -> rows 4w..4w+3; ONE 512B segment per instr.
        //      sv parity alternates; keepalive pins the OTHER parity's regs so
        //      last phase's store data is never overwritten while in flight.
        f32x2 (&sv)[4]  = (ph & 1) ? svB : svA;
        f32x2 (&svo)[4] = (ph & 1) ? svA : svB;
        asm volatile("" :: "v"(svo[0]), "v"(svo[1]), "v"(svo[2]), "v"(svo[3]));
        #pragma unroll
        for (int i = 0; i < 4; ++i) {
            const int r = w * 4 + i;
            sv[i] = *reinterpret_cast<const f32x2*>(reinterpret_cast<const char*>(obuf[ph & 1])
                    + r * 512 + ((unsigned)(l * 8) ^ ((unsigned)(r & 7) << 4)));
        }
        #pragma unroll
        for (int i = 0; i < 4; ++i) {
            const int r = w * 4 + i;
            *reinterpret_cast<f32x2*>(out + (size_t)(row0 + r) * K_CTR + colp + l * 2) = sv[i];
        }
        // obuf[ph&1] rewritten at ph+2, after barrier(ph+1): every wave's
        // ph-store ds_reads completed (lgkmcnt(0)) before crossing that barrier.
    }
}

extern "C" void kernel_launch(void* const* d_in, const int* in_sizes, int n_in,
                              void* d_out, int out_size, void* d_ws, size_t ws_size,
                              hipStream_t stream) {
    const float* x       = (const float*)d_in[0];
    const float* centers = (const float*)d_in[1];
    const float* betas   = (const float*)d_in[2];
    float* out = (float*)d_out;

    unsigned char* cbf = (unsigned char*)d_ws;                        // 256 KB fp8 fragment-major centers
    float* csq = (float*)((char*)d_ws + 262144);                      // 4 KB c_sq
    unsigned char* xb  = (unsigned char*)d_ws + 262144 + 4096;        // 4 MB fp8 As-images
    float* xsq = (float*)((char*)d_ws + 262144 + 4096 + (size_t)NSTRIP * 8192);   // 64 KB x_sq

    rbf_prep<<<2048 + K_CTR / 4, 256, 0, stream>>>(x, centers, cbf, csq, xb, xsq);
    rbf_main<<<NSTRIP, 512, 0, stream>>>(xb, xsq, cbf, csq, betas, out);
}